// Round 9
// baseline (907.146 us; speedup 1.0000x reference)
//
#include <hip/hip_runtime.h>

// HolographicConv: out = Re(ifft2(fft2(x) * W)), B == C_out == 16 -> pure
// elementwise complex multiply in frequency space per (b,c) image slice.
// 256 images of 256x256 complex64.
//
// R9: LDS-free FFT pipeline. FFT-256 = 16x16 four-step (R7's verified
// algebra) but the 16x16 transpose is a __shfl_xor butterfly (4 stages)
// inside each 16-lane group -> ZERO LDS, ZERO barriers in K1/K2.
// K1/K2 use 1-wave (64-thread) blocks, 4 columns each: waves fully
// independent, phases overlap statistically instead of summing.
// Two ws buffers with opposite layouts give K2/K3 coalesced READS:
//   K1: strided x reads (16B/row chunks) -> FFT over u -> scatter wsA[k][v]
//   K2: coalesced wsA read -> FFT over v -> mul W (coalesced) -> IFFT over v
//       -> scatter wsB[v][k]
//   K3: coalesced wsB read -> IFFT over k -> small LDS out-tile ->
//       coalesced out writes (256-thr, one sync; 20KB -> still 8 blk/CU)
// Scatters are 32B-chunked into cache-resident ws; a bijective XCD-chunked
// blockIdx swizzle puts adjacent stripes on the same XCD L2 so partial
// lines merge (also makes x's 16B-granular reads share 64B lines).

#define PI_F 3.14159265358979323846f

__device__ __forceinline__ float2 cadd(float2 a, float2 b){ return make_float2(a.x+b.x, a.y+b.y); }
__device__ __forceinline__ float2 csub(float2 a, float2 b){ return make_float2(a.x-b.x, a.y-b.y); }
__device__ __forceinline__ float2 cmul2(float2 a, float2 b){
  return make_float2(a.x*b.x - a.y*b.y, a.x*b.y + a.y*b.x);
}

template<int DIR>
__device__ __forceinline__ float2 tw16c(float cx, float cy){   // conj for DIR<0
  return make_float2(cx, (DIR > 0) ? cy : -cy);
}

template<int DIR>   // +1: e^{-i} forward, -1: e^{+i} inverse (unnormalized)
__device__ __forceinline__ void bfly1(float2& a, float2& b, float2& c, float2& d)
{
  float2 apc = cadd(a,c), amc = csub(a,c);
  float2 bpd = cadd(b,d), bmd = csub(b,d);
  float2 jb = (DIR > 0) ? make_float2(-bmd.y, bmd.x)    //  i*(b-d)
                        : make_float2( bmd.y,-bmd.x);   // -i*(b-d)
  a = cadd(apc, bpd);
  b = csub(amc, jb);
  c = csub(apc, bpd);
  d = cadd(amc, jb);
}

template<int DIR>
__device__ __forceinline__ void bfly1t(float2& a, float2& b, float2& c, float2& d,
                                       float2 w1, float2 w2, float2 w3)
{
  bfly1<DIR>(a, b, c, d);
  b = cmul2(b, w1); c = cmul2(c, w2); d = cmul2(d, w3);
}

// In-register FFT-16 over the array index (natural order in and out).
template<int DIR>
__device__ __forceinline__ void fft16(float2 (&x)[16])
{
  const float C1 = 0.92387953251128675613f, S1 = 0.38268343236508977173f;
  const float C2 = 0.70710678118654752440f;
  const float2 W1 = tw16c<DIR>( C1, -S1), W2 = tw16c<DIR>( C2, -C2);
  const float2 W3 = tw16c<DIR>( S1, -C1), W4 = tw16c<DIR>(0.f, -1.f);
  const float2 W6 = tw16c<DIR>(-C2, -C2), W9 = tw16c<DIR>(-C1,  S1);
  bfly1 <DIR>(x[0], x[4], x[8],  x[12]);
  bfly1t<DIR>(x[1], x[5], x[9],  x[13], W1, W2, W3);
  bfly1t<DIR>(x[2], x[6], x[10], x[14], W2, W4, W6);
  bfly1t<DIR>(x[3], x[7], x[11], x[15], W3, W6, W9);
  float2 y[16];
  #pragma unroll
  for (int p = 0; p < 4; ++p) {
    float2 a = x[4*p+0], b = x[4*p+1], c = x[4*p+2], d = x[4*p+3];
    bfly1<DIR>(a, b, c, d);
    y[p+0] = a; y[p+4] = b; y[p+8] = c; y[p+12] = d;
  }
  #pragma unroll
  for (int i = 0; i < 16; ++i) x[i] = y[i];
}

// x[r] *= w^r chain (w given; pass conj(w) for inverse).
__device__ __forceinline__ void twiddle_apply(float2 (&x)[16], float2 w)
{
  float2 p = w;
  x[1] = cmul2(x[1], p);
  #pragma unroll
  for (int r = 2; r < 16; ++r) { p = cmul2(p, w); x[r] = cmul2(x[r], p); }
}

// 16x16 transpose within each contiguous 16-lane group via shfl_xor
// butterfly: x_new[r]|lane m = x_old[m]|lane r. No LDS, no barriers.
__device__ __forceinline__ void transpose16s(float2 (&x)[16], int m)
{
  #pragma unroll
  for (int k = 1; k < 16; k <<= 1) {
    const bool up = (m & k) != 0;
    #pragma unroll
    for (int r0 = 0; r0 < 16; ++r0) {
      if (r0 & k) continue;
      const int r1 = r0 + k;
      float sx = up ? x[r0].x : x[r1].x;
      float sy = up ? x[r0].y : x[r1].y;
      float rx = __shfl_xor(sx, k, 64);
      float ry = __shfl_xor(sy, k, 64);
      x[r0].x = up ? rx : x[r0].x;
      x[r0].y = up ? ry : x[r0].y;
      x[r1].x = up ? x[r1].x : rx;
      x[r1].y = up ? x[r1].y : ry;
    }
  }
}

// Bijective XCD-chunked remap: HW round-robins blockIdx across 8 XCDs;
// this makes each XCD run a CONTIGUOUS stripe range (m204 formula).
__device__ __forceinline__ int swz_blk(int b, int nwg)
{
  const int xcd = b & 7, idx = b >> 3;
  const int q = nwg >> 3, r = nwg & 7;
  return (xcd < r ? xcd*(q+1) : r*(q+1) + (xcd-r)*q) + idx;
}

// ---------------- K1: FFT over u, write wsA[k][v] --------------------------
__global__ __launch_bounds__(64) void k_fft_u(const float* __restrict__ xr,
                                              const float* __restrict__ xi,
                                              float2* __restrict__ wsA)
{
  const int blk  = swz_blk(blockIdx.x, gridDim.x);
  const int imgl = blk >> 6;
  const int v0   = (blk & 63) * 4;
  const int tid = threadIdx.x, m = tid & 15, g = tid >> 4;
  const float* xrb = xr + (size_t)imgl * 65536 + v0 + g;
  const float* xib = xi + (size_t)imgl * 65536 + v0 + g;
  float2 x[16];
  #pragma unroll
  for (int j = 0; j < 16; ++j) {
    const int off = (m + 16*j) * 256;
    x[j] = make_float2(xrb[off], xib[off]);
  }
  fft16<1>(x);
  float sv, cv;
  __sincosf(-2.0f * PI_F * (float)m * (1.0f/256.0f), &sv, &cv);
  twiddle_apply(x, make_float2(cv, sv));
  transpose16s(x, m);
  fft16<1>(x);                                   // lane = k_lo, reg = k_hi
  float2* o = wsA + (size_t)imgl * 65536 + v0 + g;
  #pragma unroll
  for (int r = 0; r < 16; ++r) o[(m + 16*r) * 256] = x[r];
}

// ---------------- K2: FFT over v, * W, IFFT over v; wsA[k][v]->wsB[v][k] ---
__global__ __launch_bounds__(64) void k_mid(const float2* __restrict__ wsA,
                                            float2* __restrict__ wsB,
                                            const float* __restrict__ wr,
                                            const float* __restrict__ wi,
                                            int img0)
{
  const int blk  = swz_blk(blockIdx.x, gridDim.x);
  const int imgl = blk >> 6;
  const int k0   = (blk & 63) * 4;
  const int tid = threadIdx.x, m = tid & 15, g = tid >> 4;
  const float2* ib = wsA + (size_t)imgl * 65536 + (k0 + g) * 256;
  float2 x[16];
  #pragma unroll
  for (int j = 0; j < 16; ++j) x[j] = ib[m + 16*j];   // coalesced
  float sv, cv;
  __sincosf(-2.0f * PI_F * (float)m * (1.0f/256.0f), &sv, &cv);
  const float2 w = make_float2(cv, sv);
  fft16<1>(x);
  twiddle_apply(x, w);
  transpose16s(x, m);
  fft16<1>(x);                                   // lane = l_lo, reg = l_hi
  // W(k, l): l = m + 16r -> coalesced per column; loads fused into the mul.
  const size_t wcb = (size_t)(img0 + imgl) * 65536 + (size_t)(k0 + g) * 256 + m;
  const float* wrc = wr + wcb;
  const float* wic = wi + wcb;
  #pragma unroll
  for (int r = 0; r < 16; ++r)
    x[r] = cmul2(x[r], make_float2(wrc[16*r], wic[16*r]));
  fft16<-1>(x);
  transpose16s(x, m);
  twiddle_apply(x, make_float2(cv, -sv));
  fft16<-1>(x);                                  // lane = v_lo, reg = v_hi
  float2* ob = wsB + (size_t)imgl * 65536 + k0 + g;
  #pragma unroll
  for (int r = 0; r < 16; ++r) ob[(m + 16*r) * 256] = x[r];
}

// ---------------- K3: IFFT over k, write Re/65536 (coalesced) --------------
__global__ __launch_bounds__(256) void k_ifft_u(const float2* __restrict__ wsB,
                                                float* __restrict__ out)
{
  __shared__ float ot[256 * 20];                 // [u][16 cols] pad 20
  const int blk  = swz_blk(blockIdx.x, gridDim.x);
  const int imgl = blk >> 4;
  const int v0   = (blk & 15) * 16;
  const int tid = threadIdx.x, m = tid & 15, g = tid >> 4;
  const float2* ib = wsB + (size_t)imgl * 65536 + (v0 + g) * 256;
  float2 x[16];
  #pragma unroll
  for (int r = 0; r < 16; ++r) x[r] = ib[m + 16*r];   // coalesced
  float sv, cv;
  __sincosf(-2.0f * PI_F * (float)m * (1.0f/256.0f), &sv, &cv);
  fft16<-1>(x);
  transpose16s(x, m);
  twiddle_apply(x, make_float2(cv, -sv));
  fft16<-1>(x);                                  // lane = u_lo, reg = u_hi
  const float sc = 1.0f / 65536.0f;
  #pragma unroll
  for (int r = 0; r < 16; ++r) ot[(m + 16*r) * 20 + g] = x[r].x * sc;
  __syncthreads();
  float* ob = out + (size_t)imgl * 65536 + v0;
  const int q = tid & 3, u0 = tid >> 2;
  #pragma unroll
  for (int t = 0; t < 4; ++t) {
    const int u = u0 + 64*t;
    *(float4*)(ob + u*256 + 4*q) = *(const float4*)(ot + u*20 + 4*q);
  }
}

extern "C" void kernel_launch(void* const* d_in, const int* in_sizes, int n_in,
                              void* d_out, int out_size, void* d_ws, size_t ws_size,
                              hipStream_t stream)
{
  const float* xr = (const float*)d_in[0];
  const float* xi = (const float*)d_in[1];
  const float* wr = (const float*)d_in[2];
  const float* wi = (const float*)d_in[3];
  float* out = (float*)d_out;

  const int IMG = 256;                                     // B * C_IN
  const size_t per_img = (size_t)65536 * sizeof(float2);   // 512 KiB
  int ipc = (int)(ws_size / (2 * per_img));                // need wsA + wsB
  if (ipc < 1)   ipc = 1;
  if (ipc > IMG) ipc = IMG;
  float2* wsA = (float2*)d_ws;
  float2* wsB = wsA + (size_t)ipc * 65536;

  for (int img0 = 0; img0 < IMG; img0 += ipc) {
    const int n = (IMG - img0 < ipc) ? (IMG - img0) : ipc;
    k_fft_u <<<dim3(n*64), dim3(64),  0, stream>>>(xr + (size_t)img0*65536,
                                                   xi + (size_t)img0*65536, wsA);
    k_mid   <<<dim3(n*64), dim3(64),  0, stream>>>(wsA, wsB, wr, wi, img0);
    k_ifft_u<<<dim3(n*16), dim3(256), 0, stream>>>(wsB, out + (size_t)img0*65536);
  }
}